// Round 2
// 1653.924 us; speedup vs baseline: 1.0490x; 1.0490x over previous
//
#include <hip/hip_runtime.h>
#include <hip/hip_bf16.h>
#include <stdint.h>

// Problem constants (B=8, S=4096 -> N rows; C = M = 2048)
#define NROWS 32768
#define KDIM  2048   // inner dim of both GEMMs
#define MDIM  2048   // output cols of both GEMMs

typedef __attribute__((ext_vector_type(8))) __bf16 bf16x8;
typedef __attribute__((ext_vector_type(4))) __bf16 bf16x4;
typedef __attribute__((ext_vector_type(4))) float  f32x4;

// ---------------------------------------------------------------------------
// async global->LDS, 16B per lane, wave-uniform LDS base + lane*16
// ---------------------------------------------------------------------------
__device__ __forceinline__ void gload16(const __bf16* g, __bf16* l) {
    __builtin_amdgcn_global_load_lds(
        (__attribute__((address_space(1))) void*)(g),
        (__attribute__((address_space(3))) void*)(l), 16, 0, 0);
}

// ---------------------------------------------------------------------------
// Weight transpose + bf16 hi/lo split:  W[K][M] fp32 -> Wt_hi/Wt_lo [M][K] bf16
// ---------------------------------------------------------------------------
__global__ __launch_bounds__(256) void wsplit(const float* __restrict__ W,
                                              __bf16* __restrict__ th,
                                              __bf16* __restrict__ tl) {
    __shared__ float tile[32][33];
    const int bx = blockIdx.x & 63;   // m-tile
    const int by = blockIdx.x >> 6;   // k-tile
    const int tx = threadIdx.x & 31;
    const int ty = threadIdx.x >> 5;  // 0..7
#pragma unroll
    for (int i = 0; i < 32; i += 8)
        tile[ty + i][tx] = W[(size_t)(by * 32 + ty + i) * MDIM + bx * 32 + tx];
    __syncthreads();
#pragma unroll
    for (int i = 0; i < 32; i += 8) {
        const int m = bx * 32 + ty + i;
        const int k = by * 32 + tx;
        const float v = tile[tx][ty + i];
        const __bf16 hb = (__bf16)v;
        const __bf16 lb = (__bf16)(v - (float)hb);
        th[(size_t)m * KDIM + k] = hb;
        tl[(size_t)m * KDIM + k] = lb;
    }
}

// ---------------------------------------------------------------------------
// Fused LayerNorm + SiLU -> single bf16 plane. One block per row (C=2048).
// ---------------------------------------------------------------------------
__global__ __launch_bounds__(256) void ln_silu(const float* __restrict__ in,
                                               const float* __restrict__ g,
                                               const float* __restrict__ beta,
                                               __bf16* __restrict__ hi) {
    const int row  = blockIdx.x;
    const int tid  = threadIdx.x;
    const int lane = tid & 63;
    const int wv   = tid >> 6;
    const float* rp = in + (size_t)row * KDIM;

    const float4 v0 = ((const float4*)rp)[tid];         // cols 4t .. 4t+3
    const float4 v1 = ((const float4*)rp)[tid + 256];   // cols 1024+4t ..

    float s = v0.x + v0.y + v0.z + v0.w + v1.x + v1.y + v1.z + v1.w;
    float q = v0.x * v0.x + v0.y * v0.y + v0.z * v0.z + v0.w * v0.w +
              v1.x * v1.x + v1.y * v1.y + v1.z * v1.z + v1.w * v1.w;

#pragma unroll
    for (int off = 32; off > 0; off >>= 1) {
        s += __shfl_xor(s, off, 64);
        q += __shfl_xor(q, off, 64);
    }
    __shared__ float red[8];
    if (lane == 0) { red[wv] = s; red[4 + wv] = q; }
    __syncthreads();
    s = red[0] + red[1] + red[2] + red[3];
    q = red[4] + red[5] + red[6] + red[7];

    const float mu   = s * (1.0f / KDIM);
    const float var  = q * (1.0f / KDIM) - mu * mu;
    const float rstd = rsqrtf(var + 1e-6f);

    auto emit = [&](float4 v, int c0) {
        bf16x4 h4;
        const float xs[4] = {v.x, v.y, v.z, v.w};
#pragma unroll
        for (int j = 0; j < 4; j++) {
            const int c = c0 + j;
            const float t  = (xs[j] - mu) * rstd * g[c] + beta[c];
            const float sv = t / (1.0f + __expf(-t));
            h4[j] = (__bf16)sv;
        }
        *(bf16x4*)(hi + (size_t)row * KDIM + c0) = h4;
    };
    emit(v0, tid * 4);
    emit(v1, 1024 + tid * 4);
}

// ---------------------------------------------------------------------------
// 8-phase 256x256 2-product GEMM:
//   out[N][M] = Ah[N][K] * (Bh + Bl)[M][K]^T (+bias) (+residual)
// BK=32. LDS 112 KB: A triple-buffered (3x16KB), Bh/Bl double-buffered
// (2x32KB). 512 threads = 8 waves (2M x 4N), wave tile 128x64.
// 64 MFMA + 16 ds_read_b128 per wave per K-tile (snake quadrant order,
// all 8 B fragments held live -> zero redundant LDS reads).
// Counted vmcnt(2): issue Bh(t+1)@P1, Bl(t+1)@P2, A(t+2)@P3; end-of-iter
// vmcnt(2) drains exactly tile t+1, leaves A(t+2) in flight.
// LDS XOR swizzle (16B-slot ^= (row>>1)&3): inverse-swizzled global source
// for global_load_lds + swizzled ds_read addr (both-sides-or-neither).
// ---------------------------------------------------------------------------
#define PB   8192              // elems per plane (256 rows x 32 cols)
#define BOFF 24576             // elems: start of B region (after 3 A buffers)
#define NT   (KDIM / 32)       // 64 K-tiles

#define MM(ACC, A_, H_, L_)                                                    \
    ACC = __builtin_amdgcn_mfma_f32_16x16x32_bf16(A_, H_, ACC, 0, 0, 0);       \
    ACC = __builtin_amdgcn_mfma_f32_16x16x32_bf16(A_, L_, ACC, 0, 0, 0)

#define PHASE_PRE()                                                            \
    __builtin_amdgcn_s_barrier();                                              \
    asm volatile("s_waitcnt lgkmcnt(0)" ::: "memory");                         \
    __builtin_amdgcn_sched_barrier(0);                                         \
    __builtin_amdgcn_s_setprio(1)

#define PHASE_POST()                                                           \
    __builtin_amdgcn_s_setprio(0);                                             \
    __builtin_amdgcn_s_barrier()

__global__ __launch_bounds__(512, 2) void gemm8p(
        const __bf16* __restrict__ Ah,
        const __bf16* __restrict__ Bh, const __bf16* __restrict__ Bl,
        const float* __restrict__ bias, const float* __restrict__ res,
        float* __restrict__ out) {
    __shared__ __align__(16) __bf16 lds[57344];   // 114688 B

    const int tid  = threadIdx.x;
    const int lane = tid & 63;
    const int wv   = tid >> 6;     // 0..7
    const int wr   = wv >> 2;      // wave row 0..1  (128 rows each)
    const int wc   = wv & 3;       // wave col 0..3  (64 cols each)
    const int ml   = lane & 15;
    const int qk   = lane >> 4;    // 0..3

    // XCD-aware swizzle (nwg=1024 % 8 == 0 -> bijective). Column-major per
    // XCD: each XCD owns one 256-col weight panel (L2-resident) and sweeps
    // all 128 row tiles.
    const int bid = blockIdx.x;
    const int g   = (bid & 7) * 128 + (bid >> 3);
    const int m0  = (g & 127) * 256;                 // row tile
    const int n0  = (g >> 7) * 256;                  // col tile

    // ---- staging geometry ----
    const int srow = wv * 16 + (lane >> 2);
    const int scol = ((lane & 3) ^ ((lane >> 3) & 3)) * 8;  // inverse swizzle
    const __bf16* pA0 = Ah + (size_t)(m0 + srow) * KDIM + scol;
    const __bf16* pA1 = Ah + (size_t)(m0 + 128 + srow) * KDIM + scol;
    const __bf16* pH0 = Bh + (size_t)(n0 + srow) * KDIM + scol;
    const __bf16* pH1 = Bh + (size_t)(n0 + 128 + srow) * KDIM + scol;
    const __bf16* pL0 = Bl + (size_t)(n0 + srow) * KDIM + scol;
    const __bf16* pL1 = Bl + (size_t)(n0 + 128 + srow) * KDIM + scol;
    const int ld0 = wv * 512;           // LDS dest (elems) rows 0..127 chunk
    const int ld1 = 4096 + wv * 512;    // LDS dest rows 128..255 chunk

    // ---- fragment read offsets (swizzled ds_read side) ----
    const int cofs = (qk ^ ((ml >> 1) & 3)) * 8;
    const int aoff = (wr * 128 + ml) * 32 + cofs;
    const int boff = (wc * 64 + ml) * 32 + cofs;

    f32x4 acc[8][4] = {};

    // ---- prologue: Bh(0), Bl(0), A(0), A(1) ----
    gload16(pH0, lds + BOFF + ld0);
    gload16(pH1, lds + BOFF + ld1);
    gload16(pL0, lds + BOFF + PB + ld0);
    gload16(pL1, lds + BOFF + PB + ld1);
    gload16(pA0, lds + ld0);
    gload16(pA1, lds + ld1);
    gload16(pA0 + 32, lds + PB + ld0);
    gload16(pA1 + 32, lds + PB + ld1);
    asm volatile("s_waitcnt vmcnt(2)" ::: "memory");   // tile 0 resident
    __builtin_amdgcn_sched_barrier(0);
    __builtin_amdgcn_s_barrier();

    int ta = 0;   // A buffer of tile t
    int pa = 2;   // A buffer of tile t+2
    for (int t = 0; t < NT; ++t) {
        __bf16* const aB = lds + ta * PB;                       // A tile t
        __bf16* const hB = lds + BOFF + (t & 1) * 2 * PB;       // Bh tile t
        __bf16* const lB = hB + PB;                             // Bl tile t
        __bf16* const hN = lds + BOFF + ((t + 1) & 1) * 2 * PB; // Bh tile t+1
        const bool pfB = (t + 1) < NT;
        const bool pfA = (t + 2) < NT;
        const int  kB  = (t + 1) * 32;   // global col offset, B prefetch
        const int  kA  = (t + 2) * 32;   // global col offset, A prefetch

        bf16x8 a0, a1, a2, a3, h0, h1, h2, h3, l0, l1, l2, l3;

        // ---- phase 1: (mh0, nh0); prefetch Bh(t+1) ----
        a0 = *(const bf16x8*)(aB + aoff);
        a1 = *(const bf16x8*)(aB + aoff + 512);
        a2 = *(const bf16x8*)(aB + aoff + 1024);
        a3 = *(const bf16x8*)(aB + aoff + 1536);
        h0 = *(const bf16x8*)(hB + boff);
        h1 = *(const bf16x8*)(hB + boff + 512);
        l0 = *(const bf16x8*)(lB + boff);
        l1 = *(const bf16x8*)(lB + boff + 512);
        if (pfB) {
            gload16(pH0 + kB, hN + ld0);
            gload16(pH1 + kB, hN + ld1);
        }
        PHASE_PRE();
        MM(acc[0][0], a0, h0, l0); MM(acc[1][0], a1, h0, l0);
        MM(acc[2][0], a2, h0, l0); MM(acc[3][0], a3, h0, l0);
        MM(acc[0][1], a0, h1, l1); MM(acc[1][1], a1, h1, l1);
        MM(acc[2][1], a2, h1, l1); MM(acc[3][1], a3, h1, l1);
        PHASE_POST();

        // ---- phase 2: (mh0, nh1), reuse A; prefetch Bl(t+1) ----
        h2 = *(const bf16x8*)(hB + boff + 1024);
        h3 = *(const bf16x8*)(hB + boff + 1536);
        l2 = *(const bf16x8*)(lB + boff + 1024);
        l3 = *(const bf16x8*)(lB + boff + 1536);
        if (pfB) {
            gload16(pL0 + kB, hN + PB + ld0);
            gload16(pL1 + kB, hN + PB + ld1);
        }
        PHASE_PRE();
        MM(acc[0][2], a0, h2, l2); MM(acc[1][2], a1, h2, l2);
        MM(acc[2][2], a2, h2, l2); MM(acc[3][2], a3, h2, l2);
        MM(acc[0][3], a0, h3, l3); MM(acc[1][3], a1, h3, l3);
        MM(acc[2][3], a2, h3, l3); MM(acc[3][3], a3, h3, l3);
        PHASE_POST();

        // ---- phase 3: (mh1, nh1), reuse B; prefetch A(t+2) ----
        a0 = *(const bf16x8*)(aB + aoff + 2048);
        a1 = *(const bf16x8*)(aB + aoff + 2560);
        a2 = *(const bf16x8*)(aB + aoff + 3072);
        a3 = *(const bf16x8*)(aB + aoff + 3584);
        if (pfA) {
            gload16(pA0 + kA, lds + pa * PB + ld0);
            gload16(pA1 + kA, lds + pa * PB + ld1);
        }
        PHASE_PRE();
        MM(acc[4][2], a0, h2, l2); MM(acc[5][2], a1, h2, l2);
        MM(acc[6][2], a2, h2, l2); MM(acc[7][2], a3, h2, l2);
        MM(acc[4][3], a0, h3, l3); MM(acc[5][3], a1, h3, l3);
        MM(acc[6][3], a2, h3, l3); MM(acc[7][3], a3, h3, l3);
        PHASE_POST();

        // ---- phase 4: (mh1, nh0), zero reads; counted vmcnt ----
        PHASE_PRE();
        MM(acc[4][0], a0, h0, l0); MM(acc[5][0], a1, h0, l0);
        MM(acc[6][0], a2, h0, l0); MM(acc[7][0], a3, h0, l0);
        MM(acc[4][1], a0, h1, l1); MM(acc[5][1], a1, h1, l1);
        MM(acc[6][1], a2, h1, l1); MM(acc[7][1], a3, h1, l1);
        __builtin_amdgcn_s_setprio(0);
        if (pfA) {
            asm volatile("s_waitcnt vmcnt(2)" ::: "memory");   // tile t+1 ready
        } else if (pfB) {
            asm volatile("s_waitcnt vmcnt(0)" ::: "memory");   // final drain
        }
        __builtin_amdgcn_sched_barrier(0);
        if (pfB) __builtin_amdgcn_s_barrier();

        ta = (ta == 2) ? 0 : ta + 1;
        pa = (pa == 2) ? 0 : pa + 1;
    }

    // ---- epilogue: C/D layout col = lane&15, row = qk*4 + reg ----
#pragma unroll
    for (int i = 0; i < 8; i++) {
        const int gm = m0 + wr * 128 + (i >> 2) * 64 + (i & 3) * 16 + qk * 4;
#pragma unroll
        for (int j = 0; j < 4; j++) {
            const int gn = n0 + wc * 64 + j * 16 + ml;
            const float bv = bias[gn];
#pragma unroll
            for (int r = 0; r < 4; r++) {
                const size_t idx = (size_t)(gm + r) * MDIM + gn;
                float v = acc[i][j][r] + bv;
                if (res) v += res[idx];
                out[idx] = v;
            }
        }
    }
}

// ---------------------------------------------------------------------------
// Orchestration
//   ws layout (bytes):
//     [0,       128MB)  Ah  (activation bf16 plane, N*K)
//     [128MB,   136MB)  B1h   [136MB, 144MB) B1l
//     [144MB,   152MB)  B2h   [152MB, 160MB) B2l
// ---------------------------------------------------------------------------
extern "C" void kernel_launch(void* const* d_in, const int* in_sizes, int n_in,
                              void* d_out, int out_size, void* d_ws, size_t ws_size,
                              hipStream_t stream) {
    const float* x   = (const float*)d_in[0];
    const float* w1  = (const float*)d_in[1];
    const float* b1  = (const float*)d_in[2];
    const float* w2  = (const float*)d_in[3];
    const float* b2  = (const float*)d_in[4];
    const float* g1  = (const float*)d_in[5];
    const float* be1 = (const float*)d_in[6];
    const float* g2  = (const float*)d_in[7];
    const float* be2 = (const float*)d_in[8];
    float* out = (float*)d_out;

    char* ws = (char*)d_ws;
    const size_t PLANE = (size_t)NROWS * KDIM * 2;   // 128 MiB
    const size_t WPL   = (size_t)KDIM * MDIM * 2;    // 8 MiB
    __bf16* Ahp = (__bf16*)(ws);
    __bf16* B1h = (__bf16*)(ws + PLANE);
    __bf16* B1l = (__bf16*)(ws + PLANE + WPL);
    __bf16* B2h = (__bf16*)(ws + PLANE + 2 * WPL);
    __bf16* B2l = (__bf16*)(ws + PLANE + 3 * WPL);

    wsplit<<<4096, 256, 0, stream>>>(w1, B1h, B1l);
    wsplit<<<4096, 256, 0, stream>>>(w2, B2h, B2l);

    ln_silu<<<NROWS, 256, 0, stream>>>(x, g1, be1, Ahp);
    gemm8p<<<(NROWS / 256) * (MDIM / 256), 512, 0, stream>>>(
        Ahp, B1h, B1l, b1, nullptr, out);

    ln_silu<<<NROWS, 256, 0, stream>>>(out, g2, be2, Ahp);
    gemm8p<<<(NROWS / 256) * (MDIM / 256), 512, 0, stream>>>(
        Ahp, B2h, B2l, b2, x, out);
}

// Round 4
// 1632.093 us; speedup vs baseline: 1.0631x; 1.0134x over previous
//
#include <hip/hip_runtime.h>
#include <hip/hip_bf16.h>
#include <stdint.h>

// Problem constants (B=8, S=4096 -> N rows; C = M = 2048)
#define NROWS 32768
#define KDIM  2048   // inner dim of both GEMMs
#define MDIM  2048   // output cols of both GEMMs

typedef __attribute__((ext_vector_type(8))) __bf16 bf16x8;
typedef __attribute__((ext_vector_type(4))) __bf16 bf16x4;
typedef __attribute__((ext_vector_type(4))) float  f32x4;

// ---------------------------------------------------------------------------
// async global->LDS, 16B per lane, wave-uniform LDS base + lane*16
// ---------------------------------------------------------------------------
__device__ __forceinline__ void gload16(const __bf16* g, __bf16* l) {
    __builtin_amdgcn_global_load_lds(
        (__attribute__((address_space(1))) void*)(g),
        (__attribute__((address_space(3))) void*)(l), 16, 0, 0);
}

// ---------------------------------------------------------------------------
// Weight transpose + bf16 hi/lo split:  W[K][M] fp32 -> Wt_hi/Wt_lo [M][K] bf16
// ---------------------------------------------------------------------------
__global__ __launch_bounds__(256) void wsplit(const float* __restrict__ W,
                                              __bf16* __restrict__ th,
                                              __bf16* __restrict__ tl) {
    __shared__ float tile[32][33];
    const int bx = blockIdx.x & 63;   // m-tile
    const int by = blockIdx.x >> 6;   // k-tile
    const int tx = threadIdx.x & 31;
    const int ty = threadIdx.x >> 5;  // 0..7
#pragma unroll
    for (int i = 0; i < 32; i += 8)
        tile[ty + i][tx] = W[(size_t)(by * 32 + ty + i) * MDIM + bx * 32 + tx];
    __syncthreads();
#pragma unroll
    for (int i = 0; i < 32; i += 8) {
        const int m = bx * 32 + ty + i;
        const int k = by * 32 + tx;
        const float v = tile[tx][ty + i];
        const __bf16 hb = (__bf16)v;
        const __bf16 lb = (__bf16)(v - (float)hb);
        th[(size_t)m * KDIM + k] = hb;
        tl[(size_t)m * KDIM + k] = lb;
    }
}

// ---------------------------------------------------------------------------
// Fused LayerNorm + SiLU -> single bf16 plane. One block per row (C=2048).
// ---------------------------------------------------------------------------
__global__ __launch_bounds__(256) void ln_silu(const float* __restrict__ in,
                                               const float* __restrict__ g,
                                               const float* __restrict__ beta,
                                               __bf16* __restrict__ hi) {
    const int row  = blockIdx.x;
    const int tid  = threadIdx.x;
    const int lane = tid & 63;
    const int wv   = tid >> 6;
    const float* rp = in + (size_t)row * KDIM;

    const float4 v0 = ((const float4*)rp)[tid];         // cols 4t .. 4t+3
    const float4 v1 = ((const float4*)rp)[tid + 256];   // cols 1024+4t ..

    float s = v0.x + v0.y + v0.z + v0.w + v1.x + v1.y + v1.z + v1.w;
    float q = v0.x * v0.x + v0.y * v0.y + v0.z * v0.z + v0.w * v0.w +
              v1.x * v1.x + v1.y * v1.y + v1.z * v1.z + v1.w * v1.w;

#pragma unroll
    for (int off = 32; off > 0; off >>= 1) {
        s += __shfl_xor(s, off, 64);
        q += __shfl_xor(q, off, 64);
    }
    __shared__ float red[8];
    if (lane == 0) { red[wv] = s; red[4 + wv] = q; }
    __syncthreads();
    s = red[0] + red[1] + red[2] + red[3];
    q = red[4] + red[5] + red[6] + red[7];

    const float mu   = s * (1.0f / KDIM);
    const float var  = q * (1.0f / KDIM) - mu * mu;
    const float rstd = rsqrtf(var + 1e-6f);

    auto emit = [&](float4 v, int c0) {
        bf16x4 h4;
        const float xs[4] = {v.x, v.y, v.z, v.w};
#pragma unroll
        for (int j = 0; j < 4; j++) {
            const int c = c0 + j;
            const float t  = (xs[j] - mu) * rstd * g[c] + beta[c];
            const float sv = t / (1.0f + __expf(-t));
            h4[j] = (__bf16)sv;
        }
        *(bf16x4*)(hi + (size_t)row * KDIM + c0) = h4;
    };
    emit(v0, tid * 4);
    emit(v1, 1024 + tid * 4);
}

// ---------------------------------------------------------------------------
// Single-barrier-per-K-tile 256x256 2-product GEMM:
//   out[N][M] = Ah[N][K] * (Bh + Bl)[M][K]^T (+bias) (+residual)
// BK=32. A triple-buffered (3x16KB), Bh/Bl double-buffered (2x32KB) = 112 KB.
// 512 threads = 8 waves (2M x 4N), wave tile 128x64.
// Per tile: 6 gloads + 16 ds_read_b128 + 64 MFMA in ONE region (compiler
// schedules reads under MFMAs with fine-grained lgkmcnt; waves drift freely),
// then ONE counted vmcnt(2) (drains B(t+1)+A(t+1), keeps A(t+2) in flight)
// and ONE s_barrier. Safety: intra-tile reads (A(t), B(t) parity) are
// buffer-disjoint from intra-tile gload writes (A(t+2) buffer, B(t+1)
// parity); all reads are register-dep-gated before the barrier, so a wave
// crossing the barrier certifies its reads complete before any other wave's
// post-barrier gloads can overwrite those buffers.
// LDS XOR swizzle (16B-slot ^= (row>>1)&3): inverse-swizzled global source
// for global_load_lds + swizzled ds_read addr (both sides, round-2-proven).
// ---------------------------------------------------------------------------
#define PB_A 8192              // elems per A K-tile (256 rows x 32)
#define PB_B 8192              // elems per B plane K-tile
#define BOFF 24576             // elems: B region after 3 A buffers
#define NT   (KDIM / 32)       // 64 K-tiles

#define MM(ACC, A_, H_, L_)                                                    \
    ACC = __builtin_amdgcn_mfma_f32_16x16x32_bf16(A_, H_, ACC, 0, 0, 0);       \
    ACC = __builtin_amdgcn_mfma_f32_16x16x32_bf16(A_, L_, ACC, 0, 0, 0)

__global__ __launch_bounds__(512, 2) void gemmtp(
        const __bf16* __restrict__ Ah,
        const __bf16* __restrict__ Bh, const __bf16* __restrict__ Bl,
        const float* __restrict__ bias, const float* __restrict__ res,
        float* __restrict__ out) {
    __shared__ __align__(16) __bf16 lds[57344];   // 114688 B

    const int tid  = threadIdx.x;
    const int lane = tid & 63;
    const int wv   = tid >> 6;     // 0..7
    const int wr   = wv >> 2;      // wave row 0..1  (128 rows each)
    const int wc   = wv & 3;       // wave col 0..3  (64 cols each)
    const int ml   = lane & 15;
    const int qk   = lane >> 4;    // 0..3

    // XCD swizzle (nwg=1024 % 8 == 0 -> bijective); column-major per XCD so
    // each XCD's 2 MiB weight panel stays L2-resident.
    const int bid = blockIdx.x;
    const int g   = (bid & 7) * 128 + (bid >> 3);
    const int m0  = (g & 127) * 256;                 // row tile
    const int n0  = (g >> 7) * 256;                  // col tile

    // ---- staging geometry (inverse-swizzled global source) ----
    const int srow = wv * 16 + (lane >> 2);
    const int scol = ((lane & 3) ^ ((lane >> 3) & 3)) * 8;
    const __bf16* pA0 = Ah + (size_t)(m0 + srow) * KDIM + scol;
    const __bf16* pA1 = Ah + (size_t)(m0 + 128 + srow) * KDIM + scol;
    const __bf16* pH0 = Bh + (size_t)(n0 + srow) * KDIM + scol;
    const __bf16* pH1 = Bh + (size_t)(n0 + 128 + srow) * KDIM + scol;
    const __bf16* pL0 = Bl + (size_t)(n0 + srow) * KDIM + scol;
    const __bf16* pL1 = Bl + (size_t)(n0 + 128 + srow) * KDIM + scol;
    const int ld0 = wv * 512;           // LDS dest rows 0..127 chunk
    const int ld1 = 4096 + wv * 512;    // LDS dest rows 128..255 chunk

    // ---- fragment read offsets (swizzled ds_read side) ----
    const int cofs = (qk ^ ((ml >> 1) & 3)) * 8;
    const int aoff = (wr * 128 + ml) * 32 + cofs;
    const int boff = (wc * 64 + ml) * 32 + cofs;

    f32x4 acc[8][4] = {};

    // ---- prologue: stage B(0), A(0), A(1); leave A(1) in flight ----
    gload16(pH0, lds + BOFF + ld0);
    gload16(pH1, lds + BOFF + ld1);
    gload16(pL0, lds + BOFF + PB_B + ld0);
    gload16(pL1, lds + BOFF + PB_B + ld1);
    gload16(pA0, lds + ld0);
    gload16(pA1, lds + ld1);
    gload16(pA0 + 32, lds + PB_A + ld0);
    gload16(pA1 + 32, lds + PB_A + ld1);
    asm volatile("s_waitcnt vmcnt(2)" ::: "memory");   // B(0), A(0) resident
    __builtin_amdgcn_sched_barrier(0);
    __builtin_amdgcn_s_barrier();
    __builtin_amdgcn_sched_barrier(0);

    int ta = 0;   // A buffer index of tile t
    for (int t = 0; t < NT; ++t) {
        __bf16* const aCur = lds + ta * PB_A;
        const int tan_ = (ta == 2) ? 0 : ta + 1;
        const int pa_  = (tan_ == 2) ? 0 : tan_ + 1;
        __bf16* const bCur = lds + BOFF + ((t & 1) ? 2 * PB_B : 0);
        __bf16* const bNxt = lds + BOFF + ((t & 1) ? 0 : 2 * PB_B);
        const bool pfB = (t + 1) < NT;
        const bool pfA = (t + 2) < NT;

        // ---- fragment reads (16 x ds_read_b128), compiler-scheduled ----
        bf16x8 aL[4], aH[4], hB[4], lB[4];
        aL[0] = *(const bf16x8*)(aCur + aoff);
        aL[1] = *(const bf16x8*)(aCur + aoff + 512);
        aL[2] = *(const bf16x8*)(aCur + aoff + 1024);
        aL[3] = *(const bf16x8*)(aCur + aoff + 1536);
        hB[0] = *(const bf16x8*)(bCur + boff);
        hB[1] = *(const bf16x8*)(bCur + boff + 512);
        hB[2] = *(const bf16x8*)(bCur + boff + 1024);
        hB[3] = *(const bf16x8*)(bCur + boff + 1536);
        lB[0] = *(const bf16x8*)(bCur + PB_B + boff);
        lB[1] = *(const bf16x8*)(bCur + PB_B + boff + 512);
        lB[2] = *(const bf16x8*)(bCur + PB_B + boff + 1024);
        lB[3] = *(const bf16x8*)(bCur + PB_B + boff + 1536);
        aH[0] = *(const bf16x8*)(aCur + aoff + 2048);
        aH[1] = *(const bf16x8*)(aCur + aoff + 2560);
        aH[2] = *(const bf16x8*)(aCur + aoff + 3072);
        aH[3] = *(const bf16x8*)(aCur + aoff + 3584);

        // ---- prefetch: B(t+1) -> bNxt, A(t+2) -> pa_ buffer ----
        if (pfB) {
            const int kB = (t + 1) * 32;
            gload16(pH0 + kB, bNxt + ld0);
            gload16(pH1 + kB, bNxt + ld1);
            gload16(pL0 + kB, bNxt + PB_B + ld0);
            gload16(pL1 + kB, bNxt + PB_B + ld1);
        }
        if (pfA) {
            const int kA = (t + 2) * 32;
            gload16(pA0 + kA, lds + pa_ * PB_A + ld0);
            gload16(pA1 + kA, lds + pa_ * PB_A + ld1);
        }

        // ---- 64 MFMA (compiler inserts fine-grained lgkmcnt gates) ----
        __builtin_amdgcn_s_setprio(1);
        MM(acc[0][0], aL[0], hB[0], lB[0]); MM(acc[1][0], aL[1], hB[0], lB[0]);
        MM(acc[2][0], aL[2], hB[0], lB[0]); MM(acc[3][0], aL[3], hB[0], lB[0]);
        MM(acc[0][1], aL[0], hB[1], lB[1]); MM(acc[1][1], aL[1], hB[1], lB[1]);
        MM(acc[2][1], aL[2], hB[1], lB[1]); MM(acc[3][1], aL[3], hB[1], lB[1]);
        MM(acc[0][2], aL[0], hB[2], lB[2]); MM(acc[1][2], aL[1], hB[2], lB[2]);
        MM(acc[2][2], aL[2], hB[2], lB[2]); MM(acc[3][2], aL[3], hB[2], lB[2]);
        MM(acc[0][3], aL[0], hB[3], lB[3]); MM(acc[1][3], aL[1], hB[3], lB[3]);
        MM(acc[2][3], aL[2], hB[3], lB[3]); MM(acc[3][3], aL[3], hB[3], lB[3]);
        MM(acc[4][0], aH[0], hB[0], lB[0]); MM(acc[5][0], aH[1], hB[0], lB[0]);
        MM(acc[6][0], aH[2], hB[0], lB[0]); MM(acc[7][0], aH[3], hB[0], lB[0]);
        MM(acc[4][1], aH[0], hB[1], lB[1]); MM(acc[5][1], aH[1], hB[1], lB[1]);
        MM(acc[6][1], aH[2], hB[1], lB[1]); MM(acc[7][1], aH[3], hB[1], lB[1]);
        MM(acc[4][2], aH[0], hB[2], lB[2]); MM(acc[5][2], aH[1], hB[2], lB[2]);
        MM(acc[6][2], aH[2], hB[2], lB[2]); MM(acc[7][2], aH[3], hB[2], lB[2]);
        MM(acc[4][3], aH[0], hB[3], lB[3]); MM(acc[5][3], aH[1], hB[3], lB[3]);
        MM(acc[6][3], aH[2], hB[3], lB[3]); MM(acc[7][3], aH[3], hB[3], lB[3]);
        __builtin_amdgcn_s_setprio(0);

        // ---- tile sync: drain B(t+1)+A(t+1), keep A(t+2) in flight ----
        if (pfA) {
            asm volatile("s_waitcnt vmcnt(2)" ::: "memory");
        } else if (pfB) {
            asm volatile("s_waitcnt vmcnt(0)" ::: "memory");
        }
        __builtin_amdgcn_sched_barrier(0);
        if (pfB) {
            __builtin_amdgcn_s_barrier();
            __builtin_amdgcn_sched_barrier(0);
        }
        ta = tan_;
    }

    // ---- epilogue: C/D layout col = lane&15, row = qk*4 + reg ----
#pragma unroll
    for (int i = 0; i < 8; i++) {
        const int gm = m0 + wr * 128 + (i >> 2) * 64 + (i & 3) * 16 + qk * 4;
#pragma unroll
        for (int j = 0; j < 4; j++) {
            const int gn = n0 + wc * 64 + j * 16 + ml;
            const float bv = bias[gn];
#pragma unroll
            for (int r = 0; r < 4; r++) {
                const size_t idx = (size_t)(gm + r) * MDIM + gn;
                float v = acc[i][j][r] + bv;
                if (res) v += res[idx];
                out[idx] = v;
            }
        }
    }
}

// ---------------------------------------------------------------------------
// Orchestration
//   ws layout (bytes):
//     [0,       128MB)  Ah  (activation bf16 plane, N*K)
//     [128MB,   136MB)  B1h   [136MB, 144MB) B1l
//     [144MB,   152MB)  B2h   [152MB, 160MB) B2l
// ---------------------------------------------------------------------------
extern "C" void kernel_launch(void* const* d_in, const int* in_sizes, int n_in,
                              void* d_out, int out_size, void* d_ws, size_t ws_size,
                              hipStream_t stream) {
    const float* x   = (const float*)d_in[0];
    const float* w1  = (const float*)d_in[1];
    const float* b1  = (const float*)d_in[2];
    const float* w2  = (const float*)d_in[3];
    const float* b2  = (const float*)d_in[4];
    const float* g1  = (const float*)d_in[5];
    const float* be1 = (const float*)d_in[6];
    const float* g2  = (const float*)d_in[7];
    const float* be2 = (const float*)d_in[8];
    float* out = (float*)d_out;

    char* ws = (char*)d_ws;
    const size_t PLANE = (size_t)NROWS * KDIM * 2;   // 128 MiB
    const size_t WPL   = (size_t)KDIM * MDIM * 2;    // 8 MiB
    __bf16* Ahp = (__bf16*)(ws);
    __bf16* B1h = (__bf16*)(ws + PLANE);
    __bf16* B1l = (__bf16*)(ws + PLANE + WPL);
    __bf16* B2h = (__bf16*)(ws + PLANE + 2 * WPL);
    __bf16* B2l = (__bf16*)(ws + PLANE + 3 * WPL);

    wsplit<<<4096, 256, 0, stream>>>(w1, B1h, B1l);
    wsplit<<<4096, 256, 0, stream>>>(w2, B2h, B2l);

    ln_silu<<<NROWS, 256, 0, stream>>>(x, g1, be1, Ahp);
    gemmtp<<<(NROWS / 256) * (MDIM / 256), 512, 0, stream>>>(
        Ahp, B1h, B1l, b1, nullptr, out);

    ln_silu<<<NROWS, 256, 0, stream>>>(out, g2, be2, Ahp);
    gemmtp<<<(NROWS / 256) * (MDIM / 256), 512, 0, stream>>>(
        Ahp, B2h, B2l, b2, x, out);
}